// Round 9
// baseline (191.041 us; speedup 1.0000x reference)
//
#include <hip/hip_runtime.h>
#include <math.h>

#define BI 64
#define RR 36
#define BC 64
#define WW 50
#define DD 512
#define HH 256
#define CST 132

typedef _Float16 f16x8 __attribute__((ext_vector_type(8)));
typedef _Float16 f16x4 __attribute__((ext_vector_type(4)));
typedef float    f32x4 __attribute__((ext_vector_type(4)));
typedef float    f32x16 __attribute__((ext_vector_type(16)));

__device__ __forceinline__ float wave_sum(float v){
  #pragma unroll
  for (int off=32; off>0; off>>=1) v += __shfl_xor(v, off, 64);
  return v;
}
__device__ __forceinline__ float wave_max(float v){
  #pragma unroll
  for (int off=32; off>0; off>>=1) v = fmaxf(v, __shfl_xor(v, off, 64));
  return v;
}

// ---------------------------------------------------------------------------
// Fused kernel (round-9): sgemm 64x128 tiles for occupancy.
//  Round-8 counters: MfmaUtil 16 / VALU 17 / HBM 13 / Occ 14 -- all pipes
//  idle => latency-bound, and occupancy was GRID-limited (550 blk ~ 2.1/CU).
//  This round: sgemm tile 128x128 -> 64x128 => 900 sgemm blocks (+36 hgate
//  +64 gram = 1000 ~ 3.9/CU); buffer 24KB, dbuf 48KB -> 3 blocks/CU
//  (144KB LDS), 12 waves/CU. Same BK=32, same 1-barrier/step structure,
//  same verified layouts; only tile geometry + LDS strides + id bases move.
//  Block map: 0-35 hgate, 36-935 sgemm (bijective XCD swizzle for 900),
//  936-999 gram.
// ---------------------------------------------------------------------------
__global__ __launch_bounds__(256, 3) void sgemm_hgate_kernel(
    const float* __restrict__ imgs, const float* __restrict__ caps,
    const float* __restrict__ sw1, const float* __restrict__ hw1,
    const float* __restrict__ sb1, const float* __restrict__ hb1,
    const float* __restrict__ sw2, const float* __restrict__ hw2,
    float* __restrict__ Sp,
    float* __restrict__ drawS, float* __restrict__ drawH,
    float* __restrict__ rnraw,
    float* __restrict__ G, _Float16* __restrict__ Gfrag)
{
  __shared__ __align__(16) _Float16 lds[2*12288];   // 48 KB
  const int t = threadIdx.x, lane = t & 63, wv = t >> 6;

  if (blockIdx.x >= 36 && blockIdx.x < 936){
    // ---------------- sgemm body (64x128 tile) ----------------
    const int sg  = blockIdx.x - 36;                    // 0..899
    const int xcd = sg & 7, sidx = sg >> 3;
    const int l   = (xcd < 4 ? xcd*113 : 452 + (xcd-4)*112) + sidx;  // 0..899
    const int st  = l / 45, wi = l - st*45;             // 20 supertiles of 45
    const int mb  = (st & 3)*9 + wi/5;                  // 0..35 (64-row tile)
    const int nb  = (st >> 2)*5 + wi%5;                 // 0..24 (128-col tile)
    const int wm = wv & 1, wn = wv >> 1;

    f32x4 P[2][4], Q[2][4];
    #pragma unroll
    for (int a=0;a<2;a++)
      #pragma unroll
      for (int b=0;b<4;b++){ P[a][b]=(f32x4){0,0,0,0}; Q[a][b]=(f32x4){0,0,0,0}; }

    // staging: 12 hi/lo pairs (A tiles 0-3 from imgs, B tiles 0-7 from caps),
    // 3 pairs per wave. Buffer layout (f16): A-hi u*512 (u<4), A-lo 2048+,
    // B-hi 4096+u*512 (u<8), B-lo 8192+. 12288 f16 = 24KB/buffer.
    const int mrow = lane & 15, kq = (lane>>4)*8;
    const float* psrc[3]; int hoff[3], loff[3];
    #pragma unroll
    for (int s=0;s<3;s++){
      const int p = wv*3 + s;
      if (p < 4){
        psrc[s] = imgs + ((size_t)(mb*64 + p*16 + mrow))*DD + kq;
        hoff[s] = p*512 + lane*8;
        loff[s] = 2048 + p*512 + lane*8;
      } else {
        psrc[s] = caps + ((size_t)(nb*128 + (p-4)*16 + mrow))*DD + kq;
        hoff[s] = 4096 + (p-4)*512 + lane*8;
        loff[s] = 8192 + (p-4)*512 + lane*8;
      }
    }

    float4 va[3], vb[3];
    auto sg_load = [&](int ks){
      #pragma unroll
      for (int s=0;s<3;s++){
        const float* p = psrc[s] + ks*32;
        va[s] = *(const float4*)p;
        vb[s] = *(const float4*)(p+4);
      }
    };
    auto sg_write = [&](int bufi){
      _Float16* B = lds + bufi*12288;
      #pragma unroll
      for (int s=0;s<3;s++){
        float e[8] = {va[s].x,va[s].y,va[s].z,va[s].w,
                      vb[s].x,vb[s].y,vb[s].z,vb[s].w};
        f16x8 hv, lv;
        #pragma unroll
        for (int j=0;j<8;j++){
          _Float16 h = (_Float16)e[j];
          hv[j] = h;
          lv[j] = (_Float16)((e[j]-(float)h)*2048.0f);
        }
        *(f16x8*)&B[hoff[s]] = hv;
        *(f16x8*)&B[loff[s]] = lv;
      }
    };

    sg_load(0); sg_write(0);
    __syncthreads();

    for (int ks=0; ks<16; ks++){
      if (ks < 15) sg_load(ks+1);

      const _Float16* L = lds + (ks & 1)*12288;
      f16x8 a_h[2], a_l[2], b_h[4], b_l[4];
      #pragma unroll
      for (int x=0;x<2;x++){
        a_h[x] = *(const f16x8*)&L[        (wm*2+x)*512 + lane*8];
        a_l[x] = *(const f16x8*)&L[ 2048 + (wm*2+x)*512 + lane*8];
      }
      #pragma unroll
      for (int y=0;y<4;y++){
        b_h[y] = *(const f16x8*)&L[ 4096 + (wn*4+y)*512 + lane*8];
        b_l[y] = *(const f16x8*)&L[ 8192 + (wn*4+y)*512 + lane*8];
      }
      #pragma unroll
      for (int mi=0;mi<2;mi++)
        #pragma unroll
        for (int ni=0;ni<4;ni++){
          P[mi][ni] = __builtin_amdgcn_mfma_f32_16x16x32_f16(a_h[mi], b_h[ni], P[mi][ni],0,0,0);
          Q[mi][ni] = __builtin_amdgcn_mfma_f32_16x16x32_f16(a_h[mi], b_l[ni], Q[mi][ni],0,0,0);
          Q[mi][ni] = __builtin_amdgcn_mfma_f32_16x16x32_f16(a_l[mi], b_h[ni], Q[mi][ni],0,0,0);
        }

      if (ks < 15) sg_write((ks+1)&1);
      __syncthreads();
    }

    const int r0 = mb*64 + wm*32 + ((lane>>4)<<2);
    const int c0 = nb*128 + wn*64 + (lane&15);
    size_t pr[8]; size_t pc[4];
    #pragma unroll
    for (int mi=0;mi<2;mi++)
      #pragma unroll
      for (int reg=0;reg<4;reg++){
        unsigned row = (unsigned)(r0 + mi*16 + reg);
        unsigned i = row / 36u, rr_ = row - i*36u;
        pr[mi*4+reg] = (size_t)i*115200u + (size_t)rr_*50u;
      }
    #pragma unroll
    for (int ni=0;ni<4;ni++){
      unsigned col = (unsigned)(c0 + ni*16);
      unsigned cc = col / 50u, w = col - cc*50u;
      pc[ni] = (size_t)cc*1800u + w;
    }
    #pragma unroll
    for (int mi=0;mi<2;mi++)
      #pragma unroll
      for (int ni=0;ni<4;ni++)
        #pragma unroll
        for (int reg=0;reg<4;reg++)
          Sp[pr[mi*4+reg] + pc[ni]] =
              P[mi][ni][reg] + Q[mi][ni][reg]*(1.0f/2048.0f);
    return;
  }

  if (blockIdx.x >= 936){
    // ---------------- gram body (round-5 verified, relocated) ----------------
    float* Gt = (float*)lds;                // 64x64 f32 (16 KB of 48 KB)
    const int c = blockIdx.x - 936;         // 0..63
    const int wm = wv & 1, wn = wv >> 1;
    const float* cbase = caps + (size_t)c*WW*DD;

    f32x16 P, Q;
    #pragma unroll
    for (int e=0;e<16;e++){ P[e]=0.f; Q[e]=0.f; }

    const int r  = lane & 31;
    const int k8 = (lane >> 5)*8;
    const int wA = wm*32 + r;
    const int wB = wn*32 + r;
    const float* pA = cbase + (size_t)wA*DD + k8;
    const float* pB = cbase + (size_t)wB*DD + k8;

    for (int ks=0; ks<32; ks++){
      const int k0 = ks*16;
      float4 a0, a1, b0, b1;
      if (wA < WW){ a0 = *(const float4*)(pA + k0); a1 = *(const float4*)(pA + k0 + 4); }
      else        { a0 = (float4){0,0,0,0}; a1 = a0; }
      if (wB < WW){ b0 = *(const float4*)(pB + k0); b1 = *(const float4*)(pB + k0 + 4); }
      else        { b0 = (float4){0,0,0,0}; b1 = b0; }
      float av[8] = {a0.x,a0.y,a0.z,a0.w,a1.x,a1.y,a1.z,a1.w};
      float bw[8] = {b0.x,b0.y,b0.z,b0.w,b1.x,b1.y,b1.z,b1.w};
      f16x8 ah, al, bh, bl;
      #pragma unroll
      for (int j=0;j<8;j++){
        _Float16 h = (_Float16)av[j];
        ah[j] = h; al[j] = (_Float16)((av[j]-(float)h)*2048.0f);
        _Float16 g = (_Float16)bw[j];
        bh[j] = g; bl[j] = (_Float16)((bw[j]-(float)g)*2048.0f);
      }
      P = __builtin_amdgcn_mfma_f32_32x32x16_f16(ah, bh, P,0,0,0);
      Q = __builtin_amdgcn_mfma_f32_32x32x16_f16(ah, bl, Q,0,0,0);
      Q = __builtin_amdgcn_mfma_f32_32x32x16_f16(al, bh, Q,0,0,0);
    }

    const int col = wn*32 + (lane & 31);
    #pragma unroll
    for (int reg=0; reg<16; reg++){
      const int row = wm*32 + (reg&3) + 8*(reg>>2) + 4*(lane>>5);
      float g = P[reg] + Q[reg]*(1.0f/2048.0f);
      Gt[row*64 + col] = g;
      if (row < WW && col < WW)
        G[(size_t)c*WW*WW + row*WW + col] = g;
    }
    __syncthreads();

    #pragma unroll
    for (int tile=0; tile<4; tile++){
      int flat = t*4;
      int ks2 = flat>>9, L=(flat>>3)&63, j0=flat&7;
      const bool ones = (tile==3) && ((L&15)==2);   // frag n == 50
      int n  = tile*16 + (L&15);
      int kk = ks2*32 + ((L>>4)<<3) + j0;
      f16x4 v;
      #pragma unroll
      for (int e=0;e<4;e++)
        v[e] = ones ? (_Float16)1.0f : (_Float16)Gt[n*64 + kk + e];
      *(f16x4*)&Gfrag[(size_t)c*4096 + (tile*2+ks2)*512 + L*8 + j0] = v;
    }
    return;
  }

  // ---------------- hgate body (self-converting, round-8 verified) ----------
  const int mb = blockIdx.x >> 1;
  const int br = blockIdx.x & 1;          // 0 = soft, 1 = hard
  const int wm = wv & 1, wn = wv >> 1;
  const float* W = br ? hw1 : sw1;        // [512][256] row-major (k, n)

  f32x4 P[4][8];
  #pragma unroll
  for (int a=0;a<4;a++)
    #pragma unroll
    for (int b=0;b<8;b++) P[a][b]=(f32x4){0,0,0,0};

  const int mrow = lane & 15, kq = (lane>>4)*8;
  const float* apA = imgs + ((size_t)((mb*8 + wv*2)*16 + mrow))*DD + kq;
  const int nb0 = (wv*4)*16 + mrow;

  float4 va[2][2];
  float wreg[4][8];
  auto hg_load = [&](int ks){
    #pragma unroll
    for (int s=0;s<2;s++){
      const float* p = apA + (size_t)s*16*DD + ks*32;
      va[s][0] = *(const float4*)p;
      va[s][1] = *(const float4*)(p+4);
    }
    #pragma unroll
    for (int sb=0;sb<4;sb++){
      const float* q = W + (size_t)(ks*32 + kq)*HH + (nb0 + sb*16);
      #pragma unroll
      for (int j=0;j<8;j++) wreg[sb][j] = q[(size_t)j*HH];
    }
  };
  auto hg_write = [&](int bufi){
    _Float16* buf = lds + bufi*12288;
    #pragma unroll
    for (int s=0;s<2;s++){
      float e[8] = {va[s][0].x,va[s][0].y,va[s][0].z,va[s][0].w,
                    va[s][1].x,va[s][1].y,va[s][1].z,va[s][1].w};
      f16x8 hv;
      #pragma unroll
      for (int j=0;j<8;j++) hv[j] = (_Float16)e[j];
      *(f16x8*)&buf[(wv*2+s)*512 + lane*8] = hv;
    }
    #pragma unroll
    for (int sb=0;sb<4;sb++){
      f16x8 hv;
      #pragma unroll
      for (int j=0;j<8;j++) hv[j] = (_Float16)wreg[sb][j];
      *(f16x8*)&buf[4096 + (wv*4+sb)*512 + lane*8] = hv;
    }
  };

  hg_load(0); hg_write(0);
  __syncthreads();

  for (int ks=0; ks<16; ks++){
    if (ks < 15) hg_load(ks+1);

    const _Float16* L = lds + (ks & 1)*12288;
    f16x8 a[4], b[8];
    #pragma unroll
    for (int x=0;x<4;x++)
      a[x] = *(const f16x8*)&L[(wm*4+x)*512 + lane*8];
    #pragma unroll
    for (int y=0;y<8;y++)
      b[y] = *(const f16x8*)&L[4096 + (wn*8+y)*512 + lane*8];
    #pragma unroll
    for (int mi=0;mi<4;mi++)
      #pragma unroll
      for (int ni=0;ni<8;ni++)
        P[mi][ni] = __builtin_amdgcn_mfma_f32_16x16x32_f16(a[mi], b[ni], P[mi][ni],0,0,0);

    if (ks < 15) hg_write((ks+1)&1);
    __syncthreads();
  }

  const float* b1 = br ? hb1 : sb1;
  const float* w2 = br ? hw2 : sw2;
  float bvv[8], wvv[8];
  #pragma unroll
  for (int ni=0;ni<8;ni++){
    const int cb = wn*128 + ni*16 + (lane&15);
    bvv[ni] = b1[cb]; wvv[ni] = w2[cb];
  }
  float contrib[16];
  #pragma unroll
  for (int mi=0;mi<4;mi++)
    #pragma unroll
    for (int reg=0;reg<4;reg++){
      float cacc = 0.f;
      #pragma unroll
      for (int ni=0;ni<8;ni++)
        cacc = fmaf(fmaxf(P[mi][ni][reg] + bvv[ni], 0.f), wvv[ni], cacc);
      #pragma unroll
      for (int off=1; off<16; off<<=1) cacc += __shfl_xor(cacc, off, 64);
      contrib[mi*4+reg] = cacc;
    }

  float* red = (float*)lds;
  __syncthreads();
  if ((lane & 15) == 0){
    const int rbase = wm*64 + ((lane>>4)<<2);
    #pragma unroll
    for (int mi=0;mi<4;mi++)
      #pragma unroll
      for (int reg=0;reg<4;reg++)
        red[wn*128 + rbase + mi*16 + reg] = contrib[mi*4+reg];
  }
  __syncthreads();
  if (t < 128){
    float draw = red[t] + red[128 + t];
    (br ? drawH : drawS)[mb*128 + t] = draw;
  }

  if (br == 0){
    const int row = mb*128 + (t >> 1);
    const float* p = imgs + (size_t)row*DD + (t & 1)*256;
    float ss = 0.f;
    #pragma unroll
    for (int q=0;q<64;q++){
      float4 x = ((const float4*)p)[q];
      ss += x.x*x.x + x.y*x.y + x.z*x.z + x.w*x.w;
    }
    ss += __shfl_xor(ss, 1, 64);
    if ((t & 1) == 0) rnraw[row] = ss;
  }
}

// ---------------------------------------------------------------------------
// Epilogue v5 (round-7 verified): one wave = one (i,c) pair, in-register.
// ---------------------------------------------------------------------------
__global__ __launch_bounds__(256) void epi_kernel(
    const float* __restrict__ Sp,
    const int* __restrict__ img_lens, const int* __restrict__ cap_lens,
    const float* __restrict__ drawS, const float* __restrict__ drawH,
    const float* __restrict__ rnraw,
    const float* __restrict__ G, const _Float16* __restrict__ Gfrag,
    const float* __restrict__ sb2, const float* __restrict__ hb2,
    float* __restrict__ out)
{
  __shared__ __align__(16) _Float16 FT[4][48*72];   // per-wave F scratch
  const int t = threadIdx.x, lane = t & 63;
  const int wv = __builtin_amdgcn_readfirstlane(t >> 6);   // 0..3
  const int pair = blockIdx.x*4 + wv;                      // 0..4095
  const int i = pair >> 6, c = pair & 63;
  const int l = lane & 15, g = lane >> 4;
  const int cap_len = cap_lens[c];
  const int img_len = img_lens[i];

  // G A-frags (== stored B-frags; G symmetric): 8 x int4 per lane
  int4 gf[8];
  #pragma unroll
  for (int q=0;q<8;q++)
    gf[q] = ((const int4*)(Gfrag + (size_t)c*4096))[q*64 + lane];

  // S loads into B-frag layout: frag (nt,ks): row rr=16nt+l, w0=32ks+8g.
  const float* sbp = Sp + (size_t)i*115200 + (size_t)c*1800;
  float sv[3][16];
  #pragma unroll
  for (int nt=0;nt<3;nt++)
    #pragma unroll
    for (int ks=0;ks<2;ks++){
      const float* p = sbp + (nt*16+l)*50 + ks*32 + g*8;
      #pragma unroll
      for (int h=0;h<4;h++){
        float2 v2 = *(const float2*)(p + h*2);
        sv[nt][ks*8 + h*2]     = v2.x;
        sv[nt][ks*8 + h*2 + 1] = v2.y;
      }
    }

  // per-row stats + e16 fragments
  float avA[3]; int aiA[3]; float denA[3], tSA[3];
  f16x8 e16[3][2];
  #pragma unroll
  for (int nt=0;nt<3;nt++){
    float best = -INFINITY; int bw = 64;
    #pragma unroll
    for (int j=0;j<16;j++){
      int w = (j>>3)*32 + g*8 + (j&7);
      if (w < cap_len){
        float s = sv[nt][j];
        if (s > best){ best = s; bw = w; }
      }
    }
    #pragma unroll
    for (int off=16; off<64; off<<=1){
      float ov = __shfl_xor(best, off, 64);
      int   ow = __shfl_xor(bw,   off, 64);
      if (ov > best || (ov == best && ow < bw)){ best = ov; bw = ow; }
    }
    avA[nt] = best; aiA[nt] = (bw < 64) ? bw : 0;

    float dsum = 0.f, tsum = 0.f;
    #pragma unroll
    for (int ks=0;ks<2;ks++)
      #pragma unroll
      for (int j=0;j<8;j++){
        int w = ks*32 + g*8 + j;
        float s = sv[nt][ks*8+j];
        float e = (w < cap_len) ? __expf(10.0f*(s - best)) : 0.f;
        _Float16 eh = (_Float16)e;
        e16[nt][ks][j] = eh;
        dsum += (float)eh;
        tsum += (float)(_Float16)(e * s);
      }
    dsum += __shfl_xor(dsum,16,64); dsum += __shfl_xor(dsum,32,64);
    tsum += __shfl_xor(tsum,16,64); tsum += __shfl_xor(tsum,32,64);
    denA[nt] = dsum; tSA[nt] = tsum;
  }

  // F^T = G @ E^T  (C-layout out: col=rr_local=l, row=w'=16mt+4g+reg)
  _Float16* ft = &FT[wv][0];
  #pragma unroll
  for (int mt=0;mt<4;mt++)
    #pragma unroll
    for (int nt=0;nt<3;nt++){
      f32x4 acc = (f32x4){0,0,0,0};
      #pragma unroll
      for (int ks=0;ks<2;ks++){
        f16x8 ga = *(const f16x8*)&gf[mt*2+ks];
        acc = __builtin_amdgcn_mfma_f32_16x16x32_f16(ga, e16[nt][ks], acc,0,0,0);
      }
      f16x4 fv;
      #pragma unroll
      for (int r2=0;r2<4;r2++) fv[r2] = (_Float16)acc[r2];
      *(f16x4*)&ft[(nt*16+l)*72 + mt*16 + g*4] = fv;   // F[rr][w'] (f16)
    }

  // tQ[r] = sum_w e16[r,w] * F16[r,w]
  float tQA[3];
  #pragma unroll
  for (int nt=0;nt<3;nt++){
    float q = 0.f;
    #pragma unroll
    for (int ks=0;ks<2;ks++){
      f16x8 fv = *(const f16x8*)&ft[(nt*16+l)*72 + ks*32 + g*8];
      #pragma unroll
      for (int j=0;j<8;j++)
        q += (float)e16[nt][ks][j] * (float)fv[j];
    }
    q += __shfl_xor(q,16,64); q += __shfl_xor(q,32,64);
    tQA[nt] = q;
  }

  // final per-row scalar epilogue on g==0 lanes (rows rr = 16nt + l)
  if (lane < 16){
    const float sb2v = sb2[0], hb2v = hb2[0];
    #pragma unroll
    for (int nt=0;nt<3;nt++){
      const int rr = nt*16 + lane;
      if (rr < RR){
        const int ai = aiA[nt];
        const float av = avA[nt];
        float dh = (float)ft[rr*72 + ai];
        float hh = G[(size_t)c*WW*WW + ai*(WW+1)];
        float hv = (av > -1.0f) ? 1.f : 0.f;
        const int rg = i*RR + rr;
        float sg_ = 1.f/(1.f+__expf(-(drawS[rg] + sb2v)));
        float hg_ = 1.f/(1.f+__expf(-(drawH[rg] + hb2v)));
        float tot = sg_ + hg_ + 1e-8f;
        float gs = sg_/tot, gh = hg_/tot;
        float rx = 1.f/fmaxf(sqrtf(rnraw[rg]), 1e-12f);
        float dn = (float)(_Float16)denA[nt];
        float rd = 1.f/dn;
        float num = gs*(tSA[nt]*rd) + hv*gh*av;
        float n2  = gs*gs*(tQA[nt]*rd*rd) + hv*(2.f*gs*gh*(dh*rd) + gh*gh*hh);
        float ov  = num * rx / fmaxf(sqrtf(fmaxf(n2, 0.f)), 1e-12f);
        out[((size_t)i*BC + c)*RR + rr] = (rr < img_len) ? ov : -1.0f;
      }
    }
  }
}

// ---------------------------------------------------------------------------
// Fallback path kernels (round-1 verified), used only if ws too small.
// ---------------------------------------------------------------------------
__global__ __launch_bounds__(256) void gates_kernel(
    const float* __restrict__ imgs,
    const float* __restrict__ sw1, const float* __restrict__ sb1,
    const float* __restrict__ sw2, const float* __restrict__ sb2,
    const float* __restrict__ hw1, const float* __restrict__ hb1,
    const float* __restrict__ hw2, const float* __restrict__ hb2,
    float* __restrict__ sgn, float* __restrict__ hgn, float* __restrict__ rn)
{
  __shared__ __align__(16) float xs[8*DD];
  __shared__ float red[16*256];
  __shared__ float nr[8];
  const int t = threadIdx.x;
  const int row0 = blockIdx.x * 8;
  if (t < 8) nr[t] = 0.f;
  __syncthreads();
  const float4* src = (const float4*)(imgs + (size_t)row0*DD);
  #pragma unroll
  for (int m=0;m<4;m++){
    int n = m*256+t;
    float4 v = src[n];
    ((float4*)xs)[n] = v;
    float ss = v.x*v.x+v.y*v.y+v.z*v.z+v.w*v.w;
    atomicAdd(&nr[n>>7], ss);
  }
  __syncthreads();
  float accS[8]={0,0,0,0,0,0,0,0};
  float accH[8]={0,0,0,0,0,0,0,0};
  for (int k=0;k<DD;k+=4){
    float a0=sw1[(k+0)*HH+t], a1=sw1[(k+1)*HH+t], a2=sw1[(k+2)*HH+t], a3=sw1[(k+3)*HH+t];
    float b0=hw1[(k+0)*HH+t], b1=hw1[(k+1)*HH+t], b2=hw1[(k+2)*HH+t], b3=hw1[(k+3)*HH+t];
    #pragma unroll
    for (int r=0;r<8;r++){
      float4 x = *(const float4*)&xs[r*DD+k];
      accS[r]=fmaf(x.x,a0,accS[r]); accS[r]=fmaf(x.y,a1,accS[r]);
      accS[r]=fmaf(x.z,a2,accS[r]); accS[r]=fmaf(x.w,a3,accS[r]);
      accH[r]=fmaf(x.x,b0,accH[r]); accH[r]=fmaf(x.y,b1,accH[r]);
      accH[r]=fmaf(x.z,b2,accH[r]); accH[r]=fmaf(x.w,b3,accH[r]);
    }
  }
  const float b1s=sb1[t], b1h=hb1[t], w2s=sw2[t], w2h=hw2[t];
  #pragma unroll
  for (int r=0;r<8;r++){
    red[r*256+t]     = w2s * fmaxf(accS[r]+b1s, 0.f);
    red[(8+r)*256+t] = w2h * fmaxf(accH[r]+b1h, 0.f);
  }
  __syncthreads();
  const int wv=t>>6, ln=t&63;
  #pragma unroll
  for (int q=0;q<4;q++){
    int rr_ = wv*4+q;
    float v = red[rr_*256+ln]+red[rr_*256+ln+64]+red[rr_*256+ln+128]+red[rr_*256+ln+192];
    v = wave_sum(v);
    if (ln==0) red[rr_*256] = v;
  }
  __syncthreads();
  if (t<8){
    float os = red[t*256] + sb2[0];
    float oh = red[(8+t)*256] + hb2[0];
    float s = 1.f/(1.f+__expf(-os));
    float h = 1.f/(1.f+__expf(-oh));
    float tot = s+h+1e-8f;
    sgn[row0+t] = s/tot;
    hgn[row0+t] = h/tot;
    rn[row0+t]  = 1.f/fmaxf(sqrtf(nr[t]), 1e-12f);
  }
}

__global__ __launch_bounds__(256) void gram_fb_kernel(
    const float* __restrict__ caps, float* __restrict__ G)
{
  __shared__ __align__(16) float cs[WW*CST];
  const int c    = blockIdx.x >> 2;
  const int tile = blockIdx.x & 3;
  const int w0   = tile*13;
  const int nw   = (tile==3) ? 11 : 13;
  const int t=threadIdx.x, lane=t&63, wv=t>>6;
  const int wl = lane < WW ? lane : WW-1;
  float acc[4]={0.f,0.f,0.f,0.f};
  for (int k0=0;k0<DD;k0+=128){
    __syncthreads();
    for (int n=t;n<WW*32;n+=256){
      int row=n>>5, c4=(n&31)*4;
      *(float4*)&cs[row*CST+c4] = *(const float4*)(caps + ((size_t)c*WW+row)*DD + k0 + c4);
    }
    __syncthreads();
    for (int k=0;k<128;k+=4){
      float4 cv = *(const float4*)&cs[wl*CST+k];
      #pragma unroll
      for (int q=0;q<4;q++){
        int lw = wv + q*4;
        if (lw < nw){
          float4 bv = *(const float4*)&cs[(w0+lw)*CST+k];
          acc[q]=fmaf(bv.x,cv.x,acc[q]); acc[q]=fmaf(bv.y,cv.y,acc[q]);
          acc[q]=fmaf(bv.z,cv.z,acc[q]); acc[q]=fmaf(bv.w,cv.w,acc[q]);
        }
      }
    }
  }
  if (lane < WW){
    #pragma unroll
    for (int q=0;q<4;q++){
      int lw = wv + q*4;
      if (lw < nw) G[(size_t)c*WW*WW + (w0+lw)*WW + lane] = acc[q];
    }
  }
}

__global__ __launch_bounds__(256) void pair_kernel(
    const float* __restrict__ imgs, const float* __restrict__ caps,
    const int* __restrict__ img_lens, const int* __restrict__ cap_lens,
    const float* __restrict__ sgn, const float* __restrict__ hgn,
    const float* __restrict__ rn,
    const float* __restrict__ G, float* __restrict__ out)
{
  __shared__ __align__(16) float smem[WW*CST + 52*52 + RR*52];
  float* cs = smem;
  float* Gs = smem + WW*CST;
  float* As = Gs + 52*52;
  const int bx = blockIdx.x;
  const int i = bx >> 6, c = bx & 63;
  const int t = threadIdx.x, lane = t&63;
  const int wv = __builtin_amdgcn_readfirstlane(t>>6);
  const int wl = lane < WW ? lane : WW-1;
  const int cap_len = cap_lens[c];
  const int img_len = img_lens[i];
  for (int n=t;n<52*52;n+=256){
    int w=n/52, w2=n-w*52;
    Gs[n] = (w<WW && w2<WW) ? G[(size_t)c*WW*WW + w*WW + w2] : 0.f;
  }
  float acc[9]={0,0,0,0,0,0,0,0,0};
  const float* ib = imgs + ((size_t)i*RR + wv*9)*DD;
  for (int k0=0;k0<DD;k0+=128){
    __syncthreads();
    for (int n=t;n<WW*32;n+=256){
      int row=n>>5, c4=(n&31)*4;
      *(float4*)&cs[row*CST+c4] = *(const float4*)(caps + ((size_t)c*WW+row)*DD + k0 + c4);
    }
    __syncthreads();
    for (int k=0;k<128;k+=4){
      float4 cv = *(const float4*)&cs[wl*CST+k];
      #pragma unroll
      for (int j=0;j<9;j++){
        float4 iv = *(const float4*)(ib + j*DD + k0 + k);
        acc[j]=fmaf(iv.x,cv.x,acc[j]); acc[j]=fmaf(iv.y,cv.y,acc[j]);
        acc[j]=fmaf(iv.z,cv.z,acc[j]); acc[j]=fmaf(iv.w,cv.w,acc[j]);
      }
    }
  }
  for (int j=0;j<9;j++){
    const int r = wv*9 + j;
    const float s = acc[j];
    float av; int ai;
    if (lane < cap_len){ av = s;     ai = lane; }
    else if (lane < WW){ av = -1.0f; ai = lane; }
    else               { av = -INFINITY; ai = 64; }
    #pragma unroll
    for (int off=32; off>0; off>>=1){
      float ov = __shfl_xor(av, off, 64);
      int   oi = __shfl_xor(ai, off, 64);
      if (ov > av || (ov == av && oi < ai)){ av = ov; ai = oi; }
    }
    float zv = (lane < cap_len) ? s*10.0f : -INFINITY;
    float zm = wave_max(zv);
    float e  = (lane < cap_len) ? __expf(zv - zm) : 0.f;
    float den = wave_sum(e);
    if (lane < 52) As[r*52 + lane] = (lane < WW) ? e : 0.f;
    float m = 0.f;
    #pragma unroll
    for (int g=0; g<13; g++){
      float4 ab = *(const float4*)&As[r*52 + g*4];
      m = fmaf(ab.x, Gs[(g*4+0)*52+wl], m);
      m = fmaf(ab.y, Gs[(g*4+1)*52+wl], m);
      m = fmaf(ab.z, Gs[(g*4+2)*52+wl], m);
      m = fmaf(ab.w, Gs[(g*4+3)*52+wl], m);
    }
    float tS = wave_sum(e * s);
    float tQ = wave_sum(e * m);
    float dh = __shfl(m, ai, 64);
    float hh = Gs[ai*52 + ai];
    float hv = (ai < cap_len) ? 1.f : 0.f;
    const int rg = i*RR + r;
    float gs = sgn[rg], gh = hgn[rg], rx = rn[rg];
    float rd = 1.f/den;
    float num = gs*(tS*rd) + hv*gh*av;
    float n2  = gs*gs*(tQ*rd*rd) + hv*(2.f*gs*gh*(dh*rd) + gh*gh*hh);
    float ov  = num * rx / fmaxf(sqrtf(fmaxf(n2, 0.f)), 1e-12f);
    if (lane==0) out[((size_t)i*BC + c)*RR + r] = (r < img_len) ? ov : -1.0f;
  }
}

// ---------------------------------------------------------------------------
extern "C" void kernel_launch(void* const* d_in, const int* in_sizes, int n_in,
                              void* d_out, int out_size, void* d_ws, size_t ws_size,
                              hipStream_t stream)
{
  const float* imgs = (const float*)d_in[0];
  const float* caps = (const float*)d_in[1];
  const float* sw1  = (const float*)d_in[2];
  const float* sb1  = (const float*)d_in[3];
  const float* sw2  = (const float*)d_in[4];
  const float* sb2  = (const float*)d_in[5];
  const float* hw1  = (const float*)d_in[6];
  const float* hb1  = (const float*)d_in[7];
  const float* hw2  = (const float*)d_in[8];
  const float* hb2  = (const float*)d_in[9];
  const int* img_lens = (const int*)d_in[10];
  const int* cap_lens = (const int*)d_in[11];

  char* base = (char*)d_ws;
  float*    drawS = (float*)(base + 0);            // raw soft gate sums (2304)
  float*    drawH = (float*)(base + 9216);         // raw hard gate sums (2304)
  float*    rnraw = (float*)(base + 18432);        // raw imgs row sumsq (2304)
  float*    G     = (float*)(base + 27648);        // 640,000  -> 667,648
  _Float16* Gfrag = (_Float16*)(base + 667648);    // 524,288  -> 1,191,936
  float*    Sp    = (float*)(base + 18231296);     // 29,491,200 -> 47,722,496
  // +4KB slack: epi v5's vectorized S loads may over-read past Sp's end
  // (masked in registers); keep the tail inside the workspace.
  const size_t NEED = 47726592ull;

  float* out = (float*)d_out;

  if (ws_size >= NEED){
    hipLaunchKernelGGL(sgemm_hgate_kernel, dim3(1000), dim3(256), 0, stream,
                       imgs, caps, sw1, hw1, sb1, hb1, sw2, hw2,
                       Sp, drawS, drawH, rnraw, G, Gfrag);
    hipLaunchKernelGGL(epi_kernel, dim3(1024), dim3(256), 0, stream,
                       Sp, img_lens, cap_lens, drawS, drawH, rnraw,
                       G, Gfrag, sb2, hb2, out);
  } else {
    hipLaunchKernelGGL(gates_kernel, dim3(288), dim3(256), 0, stream,
                       imgs, sw1, sb1, sw2, sb2, hw1, hb1, hw2, hb2,
                       drawS, drawH, rnraw);
    hipLaunchKernelGGL(gram_fb_kernel, dim3(256), dim3(256), 0, stream, caps, G);
    hipLaunchKernelGGL(pair_kernel, dim3(BI*BC), dim3(256), 0, stream,
                       imgs, caps, img_lens, cap_lens, drawS, drawH, rnraw, G, out);
  }
}

// Round 10
// 142.079 us; speedup vs baseline: 1.3446x; 1.3446x over previous
//
#include <hip/hip_runtime.h>
#include <math.h>

#define BI 64
#define RR 36
#define BC 64
#define WW 50
#define DD 512
#define HH 256
#define CST 132

typedef _Float16 f16x8 __attribute__((ext_vector_type(8)));
typedef _Float16 f16x4 __attribute__((ext_vector_type(4)));
typedef float    f32x4 __attribute__((ext_vector_type(4)));
typedef float    f32x16 __attribute__((ext_vector_type(16)));

__device__ __forceinline__ float wave_sum(float v){
  #pragma unroll
  for (int off=32; off>0; off>>=1) v += __shfl_xor(v, off, 64);
  return v;
}
__device__ __forceinline__ float wave_max(float v){
  #pragma unroll
  for (int off=32; off>0; off>>=1) v = fmaxf(v, __shfl_xor(v, off, 64));
  return v;
}

// async global->LDS DMA, 16B per lane (round-3 verified).
__device__ __forceinline__ void gl_lds16(const _Float16* g, _Float16* l){
  __builtin_amdgcn_global_load_lds(
      (const __attribute__((address_space(1))) unsigned int*)g,
      (__attribute__((address_space(3))) unsigned int*)l, 16, 0, 0);
}

// ---------------------------------------------------------------------------
// PrepGram v3 (round-5 verified): prep branch 16-row tiles; gram branch =
// 64 MFMA blocks (32x32x16, layout HW-verified r4), operands from global f32.
// ---------------------------------------------------------------------------
__global__ __launch_bounds__(256) void prepgram_kernel(
    const float* __restrict__ imgs, const float* __restrict__ caps,
    const float* __restrict__ sw1, const float* __restrict__ hw1,
    _Float16* __restrict__ Ah, _Float16* __restrict__ Al,
    _Float16* __restrict__ Bh, _Float16* __restrict__ Bl,
    float* __restrict__ G, _Float16* __restrict__ Gfrag)
{
  __shared__ __align__(16) float smem[64*64];   // gram branch: Gt 64x64 f32
  if (blockIdx.x < 1504){
    int u = blockIdx.x*256 + threadIdx.x;
    _Float16 *dh, *dl; int idx;
    if (u < 144*1024){ idx = u;            dh = Ah; dl = Al; }
    else             { idx = u - 144*1024; dh = Bh; dl = Bl; }
    const int tile = idx >> 10, rem = idx & 1023, ks = rem >> 6, lane = rem & 63;
    const int k0 = ks*32 + (lane >> 4)*8;
    f16x8 hv, lv;
    if (u < 144*1024 || tile < 200){
      const float* src = (u < 144*1024) ? imgs : caps;
      const int m = tile*16 + (lane & 15);
      const float* p = src + (size_t)m*DD + k0;
      #pragma unroll
      for (int j=0;j<8;j++){
        float a = p[j];
        _Float16 h = (_Float16)a;
        hv[j] = h;
        lv[j] = (_Float16)((a - (float)h) * 2048.0f);
      }
    } else {
      const int n = (tile-200)*16 + (lane & 15);          // 0..511
      const float* src = (n < HH) ? (sw1 + n) : (hw1 + n - HH);
      #pragma unroll
      for (int j=0;j<8;j++){
        float a = src[(size_t)(k0+j)*HH];
        _Float16 h = (_Float16)a;
        hv[j] = h;
        lv[j] = (_Float16)((a - (float)h) * 2048.0f);
      }
    }
    *(f16x8*)(dh + (size_t)idx*8) = hv;
    *(f16x8*)(dl + (size_t)idx*8) = lv;
  } else {
    // ---------------- gram body v2: MFMA per caption ----------------
    float* Gt = smem;                       // 64x64 f32
    const int c = blockIdx.x - 1504;        // 0..63
    const int t = threadIdx.x, lane = t & 63, wv = t >> 6;   // 4 waves
    const int wm = wv & 1, wn = wv >> 1;    // 32-row / 32-col tile select
    const float* cbase = caps + (size_t)c*WW*DD;

    f32x16 P, Q;
    #pragma unroll
    for (int e=0;e<16;e++){ P[e]=0.f; Q[e]=0.f; }

    const int r  = lane & 31;
    const int k8 = (lane >> 5)*8;
    const int wA = wm*32 + r;               // A row (word), pad >=50
    const int wB = wn*32 + r;               // B col (word), pad >=50
    const float* pA = cbase + (size_t)wA*DD + k8;
    const float* pB = cbase + (size_t)wB*DD + k8;

    for (int ks=0; ks<32; ks++){
      const int k0 = ks*16;
      float4 a0, a1, b0, b1;
      if (wA < WW){ a0 = *(const float4*)(pA + k0); a1 = *(const float4*)(pA + k0 + 4); }
      else        { a0 = (float4){0,0,0,0}; a1 = a0; }
      if (wB < WW){ b0 = *(const float4*)(pB + k0); b1 = *(const float4*)(pB + k0 + 4); }
      else        { b0 = (float4){0,0,0,0}; b1 = b0; }
      float av[8] = {a0.x,a0.y,a0.z,a0.w,a1.x,a1.y,a1.z,a1.w};
      float bw[8] = {b0.x,b0.y,b0.z,b0.w,b1.x,b1.y,b1.z,b1.w};
      f16x8 ah, al, bh, bl;
      #pragma unroll
      for (int j=0;j<8;j++){
        _Float16 h = (_Float16)av[j];
        ah[j] = h; al[j] = (_Float16)((av[j]-(float)h)*2048.0f);
        _Float16 g = (_Float16)bw[j];
        bh[j] = g; bl[j] = (_Float16)((bw[j]-(float)g)*2048.0f);
      }
      P = __builtin_amdgcn_mfma_f32_32x32x16_f16(ah, bh, P,0,0,0);
      Q = __builtin_amdgcn_mfma_f32_32x32x16_f16(ah, bl, Q,0,0,0);
      Q = __builtin_amdgcn_mfma_f32_32x32x16_f16(al, bh, Q,0,0,0);
    }

    // C layout (HW-verified r4): col=lane&31, row=(reg&3)+8*(reg>>2)+4*(lane>>5)
    const int col = wn*32 + (lane & 31);
    #pragma unroll
    for (int reg=0; reg<16; reg++){
      const int row = wm*32 + (reg&3) + 8*(reg>>2) + 4*(lane>>5);
      float g = P[reg] + Q[reg]*(1.0f/2048.0f);
      Gt[row*64 + col] = g;
      if (row < WW && col < WW)
        G[(size_t)c*WW*WW + row*WW + col] = g;
    }
    __syncthreads();

    // Gfrag build: index-identical to round-3 (per 16-col tile), looped x4.
    #pragma unroll
    for (int tile=0; tile<4; tile++){
      int flat = t*4;
      int ks2 = flat>>9, L=(flat>>3)&63, j0=flat&7;
      const bool ones = (tile==3) && ((L&15)==2);   // frag n == 50
      int n  = tile*16 + (L&15);
      int kk = ks2*32 + ((L>>4)<<3) + j0;
      f16x4 v;
      #pragma unroll
      for (int e=0;e<4;e++)
        v[e] = ones ? (_Float16)1.0f : (_Float16)Gt[n*64 + kk + e];
      *(f16x4*)&Gfrag[(size_t)c*4096 + (tile*2+ks2)*512 + L*8 + j0] = v;
    }
  }
}

// ---------------------------------------------------------------------------
// Combined S-GEMM + gate-GEMM (round-6 verified: DMA staging + XCD-aware
// supertile swizzle).
// ---------------------------------------------------------------------------
__global__ __launch_bounds__(256, 2) void sgemm_hgate_kernel(
    const _Float16* __restrict__ Ah, const _Float16* __restrict__ Al,
    const _Float16* __restrict__ Bh, const _Float16* __restrict__ Bl,
    float* __restrict__ Sp,
    const float* __restrict__ imgs,
    const float* __restrict__ sb1, const float* __restrict__ hb1,
    const float* __restrict__ sw2, const float* __restrict__ hw2,
    float* __restrict__ drawS, float* __restrict__ drawH,
    float* __restrict__ rnraw)
{
  __shared__ _Float16 lds[2*16384];
  const int t = threadIdx.x, lane = t & 63, wv = t >> 6;

  if (blockIdx.x >= 36){
    // ---------------- sgemm body ----------------
    const int sg  = blockIdx.x - 36;                    // 0..449
    const int xcd = sg & 7, sidx = sg >> 3;
    const int l   = (xcd < 2 ? xcd*57 : 114 + (xcd-2)*56) + sidx;  // 0..449
    const int st  = l / 45, wi = l - st*45;             // supertile id / within
    const int mbg = st & 1, nbg = st >> 1;              // 2 x 5 supertile grid
    const int mb  = mbg*9 + wi/5;                       // 0..17
    const int nb  = nbg*5 + wi%5;                       // 0..24
    const int wm = wv & 1, wn = wv >> 1;

    f32x4 P[4][4], Q[4][4];
    #pragma unroll
    for (int a=0;a<4;a++)
      #pragma unroll
      for (int b=0;b<4;b++){ P[a][b]=(f32x4){0,0,0,0}; Q[a][b]=(f32x4){0,0,0,0}; }

    const _Float16* sbase = (wv==0)?Ah:(wv==1)?Al:(wv==2)?Bh:Bl;
    const size_t gtb = (size_t)((wv<2)? mb : nb)*8;
    _Float16* buf0 = lds + wv*4096;
    _Float16* buf1 = lds + 16384 + wv*4096;

    // prologue: DMA-stage ks=0 into buf0
    #pragma unroll
    for (int s=0;s<8;s++)
      gl_lds16(sbase + (((gtb+s)*16 + 0)*64 + lane)*8, buf0 + s*512);
    asm volatile("s_waitcnt vmcnt(0)" ::: "memory");
    __syncthreads();

    for (int ks=0; ks<16; ks++){
      if (ks < 15){
        _Float16* nb_ = ((ks+1) & 1) ? buf1 : buf0;
        #pragma unroll
        for (int s=0;s<8;s++)
          gl_lds16(sbase + (((gtb+s)*16 + (ks+1))*64 + lane)*8, nb_ + s*512);
      }

      const _Float16* L = lds + (ks & 1)*16384;
      f16x8 a_h[4], a_l[4], b_h[4], b_l[4];
      #pragma unroll
      for (int x=0;x<4;x++){
        a_h[x] = *(const f16x8*)&L[        (wm*4+x)*512 + lane*8];
        a_l[x] = *(const f16x8*)&L[ 4096 + (wm*4+x)*512 + lane*8];
        b_h[x] = *(const f16x8*)&L[ 8192 + (wn*4+x)*512 + lane*8];
        b_l[x] = *(const f16x8*)&L[12288 + (wn*4+x)*512 + lane*8];
      }
      #pragma unroll
      for (int mi=0;mi<4;mi++)
        #pragma unroll
        for (int ni=0;ni<4;ni++){
          P[mi][ni] = __builtin_amdgcn_mfma_f32_16x16x32_f16(a_h[mi], b_h[ni], P[mi][ni],0,0,0);
          Q[mi][ni] = __builtin_amdgcn_mfma_f32_16x16x32_f16(a_h[mi], b_l[ni], Q[mi][ni],0,0,0);
          Q[mi][ni] = __builtin_amdgcn_mfma_f32_16x16x32_f16(a_l[mi], b_h[ni], Q[mi][ni],0,0,0);
        }

      if (ks < 15)
        asm volatile("s_waitcnt vmcnt(0)" ::: "memory");  // next buf landed
      __syncthreads();
    }

    const int r0 = mb*128 + wm*64 + ((lane>>4)<<2);
    const int c0 = nb*128 + wn*64 + (lane&15);
    size_t pr[16]; size_t pc[4];
    #pragma unroll
    for (int mi=0;mi<4;mi++)
      #pragma unroll
      for (int reg=0;reg<4;reg++){
        unsigned row = (unsigned)(r0 + mi*16 + reg);
        unsigned i = row / 36u, rr_ = row - i*36u;
        pr[mi*4+reg] = (size_t)i*115200u + (size_t)rr_*50u;
      }
    #pragma unroll
    for (int ni=0;ni<4;ni++){
      unsigned col = (unsigned)(c0 + ni*16);
      unsigned cc = col / 50u, w = col - cc*50u;
      pc[ni] = (size_t)cc*1800u + w;
    }
    #pragma unroll
    for (int mi=0;mi<4;mi++)
      #pragma unroll
      for (int ni=0;ni<4;ni++)
        #pragma unroll
        for (int reg=0;reg<4;reg++)
          Sp[pr[mi*4+reg] + pc[ni]] =
              P[mi][ni][reg] + Q[mi][ni][reg]*(1.0f/2048.0f);
    return;
  }

  // ---------------- hgate body ----------------
  const int mb = blockIdx.x >> 1;
  const int br = blockIdx.x & 1;          // 0 = soft, 1 = hard
  const int wm = wv & 1, wn = wv >> 1;

  f32x4 P[4][8];
  #pragma unroll
  for (int a=0;a<4;a++)
    #pragma unroll
    for (int b=0;b<8;b++) P[a][b]=(f32x4){0,0,0,0};

  const _Float16* Bbase = Bh + (size_t)(200 + br*16)*8192;

  // prologue DMA-stage ks=0
  #pragma unroll
  for (int s=0;s<6;s++){
    const int u = wv*6 + s;
    const _Float16* src = (u < 8)
      ? (Ah    + ((size_t)((mb*8 + u)*16 + 0)*64 + lane)*8)
      : (Bbase + ((size_t)((u-8)  *16 + 0)*64 + lane)*8);
    _Float16* dst = (u < 8) ? (lds + u*512) : (lds + 4096 + (u-8)*512);
    gl_lds16(src, dst);
  }
  asm volatile("s_waitcnt vmcnt(0)" ::: "memory");
  __syncthreads();

  for (int ks=0; ks<16; ks++){
    if (ks < 15){
      _Float16* buf = lds + (((ks+1) & 1) ? 16384 : 0);
      #pragma unroll
      for (int s=0;s<6;s++){
        const int u = wv*6 + s;
        const _Float16* src = (u < 8)
          ? (Ah    + ((size_t)((mb*8 + u)*16 + (ks+1))*64 + lane)*8)
          : (Bbase + ((size_t)((u-8)  *16 + (ks+1))*64 + lane)*8);
        _Float16* dst = (u < 8) ? (buf + u*512) : (buf + 4096 + (u-8)*512);
        gl_lds16(src, dst);
      }
    }

    const _Float16* L = lds + (ks & 1)*16384;
    f16x8 a[4], b[8];
    #pragma unroll
    for (int x=0;x<4;x++)
      a[x] = *(const f16x8*)&L[(wm*4+x)*512 + lane*8];
    #pragma unroll
    for (int y=0;y<8;y++)
      b[y] = *(const f16x8*)&L[4096 + (wn*8+y)*512 + lane*8];
    #pragma unroll
    for (int mi=0;mi<4;mi++)
      #pragma unroll
      for (int ni=0;ni<8;ni++)
        P[mi][ni] = __builtin_amdgcn_mfma_f32_16x16x32_f16(a[mi], b[ni], P[mi][ni],0,0,0);

    if (ks < 15)
      asm volatile("s_waitcnt vmcnt(0)" ::: "memory");
    __syncthreads();
  }

  const float* b1 = br ? hb1 : sb1;
  const float* w2 = br ? hw2 : sw2;
  float bvv[8], wvv[8];
  #pragma unroll
  for (int ni=0;ni<8;ni++){
    const int cb = wn*128 + ni*16 + (lane&15);
    bvv[ni] = b1[cb]; wvv[ni] = w2[cb];
  }
  float contrib[16];
  #pragma unroll
  for (int mi=0;mi<4;mi++)
    #pragma unroll
    for (int reg=0;reg<4;reg++){
      float cacc = 0.f;
      #pragma unroll
      for (int ni=0;ni<8;ni++)
        cacc = fmaf(fmaxf(P[mi][ni][reg] + bvv[ni], 0.f), wvv[ni], cacc);
      #pragma unroll
      for (int off=1; off<16; off<<=1) cacc += __shfl_xor(cacc, off, 64);
      contrib[mi*4+reg] = cacc;
    }

  float* red = (float*)lds;
  if ((lane & 15) == 0){
    const int rbase = wm*64 + ((lane>>4)<<2);
    #pragma unroll
    for (int mi=0;mi<4;mi++)
      #pragma unroll
      for (int reg=0;reg<4;reg++)
        red[wn*128 + rbase + mi*16 + reg] = contrib[mi*4+reg];
  }
  __syncthreads();
  if (t < 128){
    float draw = red[t] + red[128 + t];
    (br ? drawH : drawS)[mb*128 + t] = draw;
  }

  if (br == 0){
    const int row = mb*128 + (t >> 1);
    const float* p = imgs + (size_t)row*DD + (t & 1)*256;
    float ss = 0.f;
    #pragma unroll
    for (int q=0;q<64;q++){
      float4 x = ((const float4*)p)[q];
      ss += x.x*x.x + x.y*x.y + x.z*x.z + x.w*x.w;
    }
    ss += __shfl_xor(ss, 1, 64);
    if ((t & 1) == 0) rnraw[row] = ss;
  }
}

// ---------------------------------------------------------------------------
// Epilogue v5 (round-7 verified): one wave = one (i,c) pair, in-register.
// ---------------------------------------------------------------------------
__global__ __launch_bounds__(256) void epi_kernel(
    const float* __restrict__ Sp,
    const int* __restrict__ img_lens, const int* __restrict__ cap_lens,
    const float* __restrict__ drawS, const float* __restrict__ drawH,
    const float* __restrict__ rnraw,
    const float* __restrict__ G, const _Float16* __restrict__ Gfrag,
    const float* __restrict__ sb2, const float* __restrict__ hb2,
    float* __restrict__ out)
{
  __shared__ __align__(16) _Float16 FT[4][48*72];   // per-wave F scratch
  const int t = threadIdx.x, lane = t & 63;
  const int wv = __builtin_amdgcn_readfirstlane(t >> 6);   // 0..3
  const int pair = blockIdx.x*4 + wv;                      // 0..4095
  const int i = pair >> 6, c = pair & 63;
  const int l = lane & 15, g = lane >> 4;
  const int cap_len = cap_lens[c];
  const int img_len = img_lens[i];

  // G A-frags (== stored B-frags; G symmetric): 8 x int4 per lane
  int4 gf[8];
  #pragma unroll
  for (int q=0;q<8;q++)
    gf[q] = ((const int4*)(Gfrag + (size_t)c*4096))[q*64 + lane];

  // S loads into B-frag layout: frag (nt,ks): row rr=16nt+l, w0=32ks+8g.
  const float* sbp = Sp + (size_t)i*115200 + (size_t)c*1800;
  float sv[3][16];
  #pragma unroll
  for (int nt=0;nt<3;nt++)
    #pragma unroll
    for (int ks=0;ks<2;ks++){
      const float* p = sbp + (nt*16+l)*50 + ks*32 + g*8;
      #pragma unroll
      for (int h=0;h<4;h++){
        float2 v2 = *(const float2*)(p + h*2);
        sv[nt][ks*8 + h*2]     = v2.x;
        sv[nt][ks*8 + h*2 + 1] = v2.y;
      }
    }

  // per-row stats + e16 fragments
  float avA[3]; int aiA[3]; float denA[3], tSA[3];
  f16x8 e16[3][2];
  #pragma unroll
  for (int nt=0;nt<3;nt++){
    float best = -INFINITY; int bw = 64;
    #pragma unroll
    for (int j=0;j<16;j++){
      int w = (j>>3)*32 + g*8 + (j&7);
      if (w < cap_len){
        float s = sv[nt][j];
        if (s > best){ best = s; bw = w; }
      }
    }
    #pragma unroll
    for (int off=16; off<64; off<<=1){
      float ov = __shfl_xor(best, off, 64);
      int   ow = __shfl_xor(bw,   off, 64);
      if (ov > best || (ov == best && ow < bw)){ best = ov; bw = ow; }
    }
    avA[nt] = best; aiA[nt] = (bw < 64) ? bw : 0;

    float dsum = 0.f, tsum = 0.f;
    #pragma unroll
    for (int ks=0;ks<2;ks++)
      #pragma unroll
      for (int j=0;j<8;j++){
        int w = ks*32 + g*8 + j;
        float s = sv[nt][ks*8+j];
        float e = (w < cap_len) ? __expf(10.0f*(s - best)) : 0.f;
        _Float16 eh = (_Float16)e;
        e16[nt][ks][j] = eh;
        dsum += (float)eh;
        tsum += (float)(_Float16)(e * s);
      }
    dsum += __shfl_xor(dsum,16,64); dsum += __shfl_xor(dsum,32,64);
    tsum += __shfl_xor(tsum,16,64); tsum += __shfl_xor(tsum,32,64);
    denA[nt] = dsum; tSA[nt] = tsum;
  }

  // F^T = G @ E^T  (C-layout out: col=rr_local=l, row=w'=16mt+4g+reg)
  _Float16* ft = &FT[wv][0];
  #pragma unroll
  for (int mt=0;mt<4;mt++)
    #pragma unroll
    for (int nt=0;nt<3;nt++){
      f32x4 acc = (f32x4){0,0,0,0};
      #pragma unroll
      for (int ks=0;ks<2;ks++){
        f16x8 ga = *(const f16x8*)&gf[mt*2+ks];
        acc = __builtin_amdgcn_mfma_f32_16x16x32_f16(ga, e16[nt][ks], acc,0,0,0);
      }
      f16x4 fv;
      #pragma unroll
      for (int r2=0;r2<4;r2++) fv[r2] = (_Float16)acc[r2];
      *(f16x4*)&ft[(nt*16+l)*72 + mt*16 + g*4] = fv;   // F[rr][w'] (f16)
    }

  // tQ[r] = sum_w e16[r,w] * F16[r,w]
  float tQA[3];
  #pragma unroll
  for (int nt=0;nt<3;nt++){
    float q = 0.f;
    #pragma unroll
    for (int ks=0;ks<2;ks++){
      f16x8 fv = *(const f16x8*)&ft[(nt*16+l)*72 + ks*32 + g*8];
      #pragma unroll
      for (int j=0;j<8;j++)
        q += (float)e16[nt][ks][j] * (float)fv[j];
    }
    q += __shfl_xor(q,16,64); q += __shfl_xor(q,32,64);
    tQA[nt] = q;
  }

  // final per-row scalar epilogue on g==0 lanes (rows rr = 16nt + l)
  if (lane < 16){
    const float sb2v = sb2[0], hb2v = hb2[0];
    #pragma unroll
    for (int nt=0;nt<3;nt++){
      const int rr = nt*16 + lane;
      if (rr < RR){
        const int ai = aiA[nt];
        const float av = avA[nt];
        float dh = (float)ft[rr*72 + ai];
        float hh = G[(size_t)c*WW*WW + ai*(WW+1)];
        float hv = (av > -1.0f) ? 1.f : 0.f;
        const int rg = i*RR + rr;
        float sg_ = 1.f/(1.f+__expf(-(drawS[rg] + sb2v)));
        float hg_ = 1.f/(1.f+__expf(-(drawH[rg] + hb2v)));
        float tot = sg_ + hg_ + 1e-8f;
        float gs = sg_/tot, gh = hg_/tot;
        float rx = 1.f/fmaxf(sqrtf(rnraw[rg]), 1e-12f);
        float dn = (float)(_Float16)denA[nt];
        float rd = 1.f/dn;
        float num = gs*(tSA[nt]*rd) + hv*gh*av;
        float n2  = gs*gs*(tQA[nt]*rd*rd) + hv*(2.f*gs*gh*(dh*rd) + gh*gh*hh);
        float ov  = num * rx / fmaxf(sqrtf(fmaxf(n2, 0.f)), 1e-12f);
        out[((size_t)i*BC + c)*RR + rr] = (rr < img_len) ? ov : -1.0f;
      }
    }
  }
}

// ---------------------------------------------------------------------------
// Fallback path kernels (round-1 verified), used only if ws too small.
// ---------------------------------------------------------------------------
__global__ __launch_bounds__(256) void gates_kernel(
    const float* __restrict__ imgs,
    const float* __restrict__ sw1, const float* __restrict__ sb1,
    const float* __restrict__ sw2, const float* __restrict__ sb2,
    const float* __restrict__ hw1, const float* __restrict__ hb1,
    const float* __restrict__ hw2, const float* __restrict__ hb2,
    float* __restrict__ sgn, float* __restrict__ hgn, float* __restrict__ rn)
{
  __shared__ __align__(16) float xs[8*DD];
  __shared__ float red[16*256];
  __shared__ float nr[8];
  const int t = threadIdx.x;
  const int row0 = blockIdx.x * 8;
  if (t < 8) nr[t] = 0.f;
  __syncthreads();
  const float4* src = (const float4*)(imgs + (size_t)row0*DD);
  #pragma unroll
  for (int m=0;m<4;m++){
    int n = m*256+t;
    float4 v = src[n];
    ((float4*)xs)[n] = v;
    float ss = v.x*v.x+v.y*v.y+v.z*v.z+v.w*v.w;
    atomicAdd(&nr[n>>7], ss);
  }
  __syncthreads();
  float accS[8]={0,0,0,0,0,0,0,0};
  float accH[8]={0,0,0,0,0,0,0,0};
  for (int k=0;k<DD;k+=4){
    float a0=sw1[(k+0)*HH+t], a1=sw1[(k+1)*HH+t], a2=sw1[(k+2)*HH+t], a3=sw1[(k+3)*HH+t];
    float b0=hw1[(k+0)*HH+t], b1=hw1[(k+1)*HH+t], b2=hw1[(k+2)*HH+t], b3=hw1[(k+3)*HH+t];
    #pragma unroll
    for (int r=0;r<8;r++){
      float4 x = *(const float4*)&xs[r*DD+k];
      accS[r]=fmaf(x.x,a0,accS[r]); accS[r]=fmaf(x.y,a1,accS[r]);
      accS[r]=fmaf(x.z,a2,accS[r]); accS[r]=fmaf(x.w,a3,accS[r]);
      accH[r]=fmaf(x.x,b0,accH[r]); accH[r]=fmaf(x.y,b1,accH[r]);
      accH[r]=fmaf(x.z,b2,accH[r]); accH[r]=fmaf(x.w,b3,accH[r]);
    }
  }
  const float b1s=sb1[t], b1h=hb1[t], w2s=sw2[t], w2h=hw2[t];
  #pragma unroll
  for (int r=0;r<8;r++){
    red[r*256+t]     = w2s * fmaxf(accS[r]+b1s, 0.f);
    red[(8+r)*256+t] = w2h * fmaxf(accH[r]+b1h, 0.f);
  }
  __syncthreads();
  const int wv=t>>6, ln=t&63;
  #pragma unroll
  for (int q=0;q<4;q++){
    int rr_ = wv*4+q;
    float v = red[rr_*256+ln]+red[rr_*256+ln+64]+red[rr_*256+ln+128]+red[rr_*256+ln+192];
    v = wave_sum(v);
    if (ln==0) red[rr_*256] = v;
  }
  __syncthreads();
  if (t<8){
    float os = red[t*256] + sb2[0];
    float oh = red[(8+t)*256] + hb2[0];
    float s = 1.f/(1.f+__expf(-os));
    float h = 1.f/(1.f+__expf(-oh));
    float tot = s+h+1e-8f;
    sgn[row0+t] = s/tot;
    hgn[row0+t] = h/tot;
    rn[row0+t]  = 1.f/fmaxf(sqrtf(nr[t]), 1e-12f);
  }
}

__global__ __launch_bounds__(256) void gram_fb_kernel(
    const float* __restrict__ caps, float* __restrict__ G)
{
  __shared__ __align__(16) float cs[WW*CST];
  const int c    = blockIdx.x >> 2;
  const int tile = blockIdx.x & 3;
  const int w0   = tile*13;
  const int nw   = (tile==3) ? 11 : 13;
  const int t=threadIdx.x, lane=t&63, wv=t>>6;
  const int wl = lane < WW ? lane : WW-1;
  float acc[4]={0.f,0.f,0.f,0.f};
  for (int k0=0;k0<DD;k0+=128){
    __syncthreads();
    for (int n=t;n<WW*32;n+=256){
      int row=n>>5, c4=(n&31)*4;
      *(float4*)&cs[row*CST+c4] = *(const float4*)(caps + ((size_t)c*WW+row)*DD + k0 + c4);
    }
    __syncthreads();
    for (int k=0;k<128;k+=4){
      float4 cv = *(const float4*)&cs[wl*CST+k];
      #pragma unroll
      for (int q=0;q<4;q++){
        int lw = wv + q*4;
        if (lw < nw){
          float4 bv = *(const float4*)&cs[(w0+lw)*CST+k];
          acc[q]=fmaf(bv.x,cv.x,acc[q]); acc[q]=fmaf(bv.y,cv.y,acc[q]);
          acc[q]=fmaf(bv.z,cv.z,acc[q]); acc[q]=fmaf(bv.w,cv.w,acc[q]);
        }
      }
    }
  }
  if (lane < WW){
    #pragma unroll
    for (int q=0;q<4;q++){
      int lw = wv + q*4;
      if (lw < nw) G[(size_t)c*WW*WW + (w0+lw)*WW + lane] = acc[q];
    }
  }
}

__global__ __launch_bounds__(256) void pair_kernel(
    const float* __restrict__ imgs, const float* __restrict__ caps,
    const int* __restrict__ img_lens, const int* __restrict__ cap_lens,
    const float* __restrict__ sgn, const float* __restrict__ hgn,
    const float* __restrict__ rn,
    const float* __restrict__ G, float* __restrict__ out)
{
  __shared__ __align__(16) float smem[WW*CST + 52*52 + RR*52];
  float* cs = smem;
  float* Gs = smem + WW*CST;
  float* As = Gs + 52*52;
  const int bx = blockIdx.x;
  const int i = bx >> 6, c = bx & 63;
  const int t = threadIdx.x, lane = t&63;
  const int wv = __builtin_amdgcn_readfirstlane(t>>6);
  const int wl = lane < WW ? lane : WW-1;
  const int cap_len = cap_lens[c];
  const int img_len = img_lens[i];
  for (int n=t;n<52*52;n+=256){
    int w=n/52, w2=n-w*52;
    Gs[n] = (w<WW && w2<WW) ? G[(size_t)c*WW*WW + w*WW + w2] : 0.f;
  }
  float acc[9]={0,0,0,0,0,0,0,0,0};
  const float* ib = imgs + ((size_t)i*RR + wv*9)*DD;
  for (int k0=0;k0<DD;k0+=128){
    __syncthreads();
    for (int n=t;n<WW*32;n+=256){
      int row=n>>5, c4=(n&31)*4;
      *(float4*)&cs[row*CST+c4] = *(const float4*)(caps + ((size_t)c*WW+row)*DD + k0 + c4);
    }
    __syncthreads();
    for (int k=0;k<128;k+=4){
      float4 cv = *(const float4*)&cs[wl*CST+k];
      #pragma unroll
      for (int j=0;j<9;j++){
        float4 iv = *(const float4*)(ib + j*DD + k0 + k);
        acc[j]=fmaf(iv.x,cv.x,acc[j]); acc[j]=fmaf(iv.y,cv.y,acc[j]);
        acc[j]=fmaf(iv.z,cv.z,acc[j]); acc[j]=fmaf(iv.w,cv.w,acc[j]);
      }
    }
  }
  for (int j=0;j<9;j++){
    const int r = wv*9 + j;
    const float s = acc[j];
    float av; int ai;
    if (lane < cap_len){ av = s;     ai = lane; }
    else if (lane < WW){ av = -1.0f; ai = lane; }
    else               { av = -INFINITY; ai = 64; }
    #pragma unroll
    for (int off=32; off>0; off>>=1){
      float ov = __shfl_xor(av, off, 64);
      int   oi = __shfl_xor(ai, off, 64);
      if (ov > av || (ov == av && oi < ai)){ av = ov; ai = oi; }
    }
    float zv = (lane < cap_len) ? s*10.0f : -INFINITY;
    float zm = wave_max(zv);
    float e  = (lane < cap_len) ? __expf(zv - zm) : 0.f;
    float den = wave_sum(e);
    if (lane < 52) As[r*52 + lane] = (lane < WW) ? e : 0.f;
    float m = 0.f;
    #pragma unroll
    for (int g=0; g<13; g++){
      float4 ab = *(const float4*)&As[r*52 + g*4];
      m = fmaf(ab.x, Gs[(g*4+0)*52+wl], m);
      m = fmaf(ab.y, Gs[(g*4+1)*52+wl], m);
      m = fmaf(ab.z, Gs[(g*4+2)*52+wl], m);
      m = fmaf(ab.w, Gs[(g*4+3)*52+wl], m);
    }
    float tS = wave_sum(e * s);
    float tQ = wave_sum(e * m);
    float dh = __shfl(m, ai, 64);
    float hh = Gs[ai*52 + ai];
    float hv = (ai < cap_len) ? 1.f : 0.f;
    const int rg = i*RR + r;
    float gs = sgn[rg], gh = hgn[rg], rx = rn[rg];
    float rd = 1.f/den;
    float num = gs*(tS*rd) + hv*gh*av;
    float n2  = gs*gs*(tQ*rd*rd) + hv*(2.f*gs*gh*(dh*rd) + gh*gh*hh);
    float ov  = num * rx / fmaxf(sqrtf(fmaxf(n2, 0.f)), 1e-12f);
    if (lane==0) out[((size_t)i*BC + c)*RR + r] = (r < img_len) ? ov : -1.0f;
  }
}

// ---------------------------------------------------------------------------
extern "C" void kernel_launch(void* const* d_in, const int* in_sizes, int n_in,
                              void* d_out, int out_size, void* d_ws, size_t ws_size,
                              hipStream_t stream)
{
  const float* imgs = (const float*)d_in[0];
  const float* caps = (const float*)d_in[1];
  const float* sw1  = (const float*)d_in[2];
  const float* sb1  = (const float*)d_in[3];
  const float* sw2  = (const float*)d_in[4];
  const float* sb2  = (const float*)d_in[5];
  const float* hw1  = (const float*)d_in[6];
  const float* hb1  = (const float*)d_in[7];
  const float* hw2  = (const float*)d_in[8];
  const float* hb2  = (const float*)d_in[9];
  const int* img_lens = (const int*)d_in[10];
  const int* cap_lens = (const int*)d_in[11];

  char* base = (char*)d_ws;
  float*    drawS = (float*)(base + 0);            // raw soft gate sums (2304)
  float*    drawH = (float*)(base + 9216);         // raw hard gate sums (2304)
  float*    rnraw = (float*)(base + 18432);        // raw imgs row sumsq (2304)
  float*    G     = (float*)(base + 27648);        // 640,000  -> 667,648
  _Float16* Gfrag = (_Float16*)(base + 667648);    // 524,288  -> 1,191,936
  _Float16* Ah    = (_Float16*)(base + 1191936);   // 2,359,296 -> 3,551,232
  _Float16* Al    = (_Float16*)(base + 3551232);   // 2,359,296 -> 5,910,528
  _Float16* Bh    = (_Float16*)(base + 5910528);   // 3,801,088 -> 9,711,616
  _Float16* Bl    = (_Float16*)(base + 9711616);   // 3,801,088 -> 13,512,704
  float*    Sp    = (float*)(base + 18231296);     // 29,491,200 -> 47,722,496
  // +4KB slack: epi v5's vectorized S loads may over-read past Sp's end
  // (masked in registers); keep the tail inside the workspace.
  const size_t NEED = 47726592ull;

  float* out = (float*)d_out;

  if (ws_size >= NEED){
    hipLaunchKernelGGL(prepgram_kernel, dim3(1568), dim3(256), 0, stream,
                       imgs, caps, sw1, hw1, Ah, Al, Bh, Bl, G, Gfrag);
    hipLaunchKernelGGL(sgemm_hgate_kernel, dim3(486), dim3(256), 0, stream,
                       Ah, Al, Bh, Bl, Sp,
                       imgs, sb1, hb1, sw2, hw2, drawS, drawH, rnraw);
    hipLaunchKernelGGL(epi_kernel, dim3(1024), dim3(256), 0, stream,
                       Sp, img_lens, cap_lens, drawS, drawH, rnraw,
                       G, Gfrag, sb2, hb2, out);
  } else {
    hipLaunchKernelGGL(gates_kernel, dim3(288), dim3(256), 0, stream,
                       imgs, sw1, sb1, sw2, sb2, hw1, hb1, hw2, hb2,
                       drawS, drawH, rnraw);
    hipLaunchKernelGGL(gram_fb_kernel, dim3(256), dim3(256), 0, stream, caps, G);
    hipLaunchKernelGGL(pair_kernel, dim3(BI*BC), dim3(256), 0, stream,
                       imgs, caps, img_lens, cap_lens, drawS, drawH, rnraw, G, out);
  }
}